// Round 2
// baseline (1201.596 us; speedup 1.0000x reference)
//
#include <hip/hip_runtime.h>
#include <math.h>

typedef __bf16 bf16;
typedef bf16 bf16x4 __attribute__((ext_vector_type(4)));
typedef bf16 bf16x8 __attribute__((ext_vector_type(8)));
typedef float f32x4 __attribute__((ext_vector_type(4)));

#define NTOK 8192      // B*T
#define CDIM 1024
#define EXP 8
#define DFF 4096
#define BM 256
#define BN 256
#define BK 64

__device__ __forceinline__ void gld_lds16(const bf16* g, bf16* l) {
  __builtin_amdgcn_global_load_lds(
      (const __attribute__((address_space(1))) unsigned int*)g,
      (__attribute__((address_space(3))) unsigned int*)l, 16, 0, 0);
}

// ---------------- x fp32 -> bf16 convert (one-shot) ----------------
__global__ __launch_bounds__(256) void convert_x(const float* __restrict__ in,
                                                 bf16* __restrict__ out) {
  int idx = (blockIdx.x * 256 + threadIdx.x) * 8;
  float4 a = *(const float4*)(in + idx);
  float4 b = *(const float4*)(in + idx + 4);
  bf16x8 v;
  v[0] = (bf16)a.x; v[1] = (bf16)a.y; v[2] = (bf16)a.z; v[3] = (bf16)a.w;
  v[4] = (bf16)b.x; v[5] = (bf16)b.y; v[6] = (bf16)b.z; v[7] = (bf16)b.w;
  *(bf16x8*)(out + idx) = v;
}

// ---------------- transpose + fp32->bf16 convert ----------------
// in: per-expert [R][Cin] fp32, out: per-expert [Cin][R] bf16
__global__ __launch_bounds__(256) void transpose_cvt(
    const float* __restrict__ in, bf16* __restrict__ out, int R, int Cin) {
  __shared__ float tile[32][33];
  int e = blockIdx.z;
  const float* ip = in + (size_t)e * R * Cin;
  bf16* op = out + (size_t)e * R * Cin;
  int c0 = blockIdx.x * 32, r0 = blockIdx.y * 32;
  int tx = threadIdx.x & 31, ty = threadIdx.x >> 5;  // ty in 0..7
#pragma unroll
  for (int i = 0; i < 4; i++)
    tile[ty + 8 * i][tx] = ip[(size_t)(r0 + ty + 8 * i) * Cin + c0 + tx];
  __syncthreads();
  int c = threadIdx.x >> 3, r4 = (threadIdx.x & 7) * 4;
  bf16x4 v;
  v[0] = (bf16)tile[r4][c];
  v[1] = (bf16)tile[r4 + 1][c];
  v[2] = (bf16)tile[r4 + 2][c];
  v[3] = (bf16)tile[r4 + 3][c];
  *(bf16x4*)&op[(size_t)(c0 + c) * R + r0 + r4] = v;
}

// ---------------- router: logits -> softmax -> top2 -> lists ----------------
__global__ __launch_bounds__(256) void router_kernel(
    const float* __restrict__ x, const float* __restrict__ rw,
    const float* __restrict__ rb, unsigned int* __restrict__ cnt,
    int* __restrict__ list, float* __restrict__ wq) {
  int wave = threadIdx.x >> 6, lane = threadIdx.x & 63;
  int t = blockIdx.x * 4 + wave;
  if (t >= NTOK) return;
  const float* xr = x + (size_t)t * CDIM;
  float acc[8] = {0.f, 0.f, 0.f, 0.f, 0.f, 0.f, 0.f, 0.f};
  for (int c = lane; c < CDIM; c += 64) {
    float xv = xr[c];
    const float4* rp = (const float4*)(rw + c * 8);
    float4 r0 = rp[0], r1 = rp[1];
    acc[0] += xv * r0.x; acc[1] += xv * r0.y;
    acc[2] += xv * r0.z; acc[3] += xv * r0.w;
    acc[4] += xv * r1.x; acc[5] += xv * r1.y;
    acc[6] += xv * r1.z; acc[7] += xv * r1.w;
  }
#pragma unroll
  for (int e = 0; e < 8; e++)
#pragma unroll
    for (int off = 32; off; off >>= 1) acc[e] += __shfl_down(acc[e], off);
  if (lane == 0) {
    float p[8], mx = -1e30f;
#pragma unroll
    for (int e = 0; e < 8; e++) { p[e] = acc[e] + rb[e]; mx = fmaxf(mx, p[e]); }
    float s = 0.f;
#pragma unroll
    for (int e = 0; e < 8; e++) { p[e] = expf(p[e] - mx); s += p[e]; }
    float inv = 1.0f / s;
#pragma unroll
    for (int e = 0; e < 8; e++) p[e] *= inv;
    int i1 = 0;
#pragma unroll
    for (int e = 1; e < 8; e++) if (p[e] > p[i1]) i1 = e;
    int i2 = (i1 == 0) ? 1 : 0;
#pragma unroll
    for (int e = 0; e < 8; e++) if (e != i1 && p[e] > p[i2]) i2 = e;
    unsigned s0 = atomicAdd(&cnt[i1], 1u);
    list[i1 * NTOK + s0] = t * 2;
    unsigned s1 = atomicAdd(&cnt[i2], 1u);
    list[i2 * NTOK + s1] = t * 2 + 1;
    wq[t * 2] = p[i1];
    wq[t * 2 + 1] = p[i2];
  }
}

// ---------------- GEMM1: h[enc] = gelu(xb[t] @ w1[e] + b1[e]) ----------------
// 256x256 tile, BK=64, 512 thr (8 waves 2Mx4N), chunk-XOR swizzled LDS,
// XCD-chunked block swizzle. A: gathered xb rows, B: w1b[e]=[DFF][C] (B^T).
__global__ __launch_bounds__(512, 2) void gemm1_kernel(
    const bf16* __restrict__ xb, const bf16* __restrict__ w1b,
    const float* __restrict__ b1, const int* __restrict__ list,
    const unsigned int* __restrict__ cnt, bf16* __restrict__ h) {
  // grid = 16 x 32 x 8 = 4096 blocks; chunk = 512 per XCD
  int bid = blockIdx.x + 16 * (blockIdx.y + 32 * blockIdx.z);
  int wg = (bid & 7) * 512 + (bid >> 3);
  int n0 = (wg & 15) * BN;
  int mt = (wg >> 4) & 31;
  int e = wg >> 9;
  int count = (int)min(cnt[e], (unsigned)NTOK);
  int m0 = mt * BM;
  if (m0 >= count) return;

  __shared__ __align__(16) bf16 As[BM][BK];
  __shared__ __align__(16) bf16 Bs[BN][BK];

  int tid = threadIdx.x;
  int w = tid >> 6, l = tid & 63;
  int lhi = l >> 3, llo = l & 7;
  int w8l = w * 8 + lhi;          // row within 64-row pass group
  int dst8 = llo * 8;             // linear LDS dest col (elems)
  int sc8 = (llo ^ lhi) * 8;      // pre-swizzled global source col (elems)

  const int* lp = list + e * NTOK;
  const bf16* aptr[4];
  const bf16* bptr[4];
#pragma unroll
  for (int p = 0; p < 4; p++) {
    int row = p * 64 + w8l;
    int enc = lp[min(m0 + row, count - 1)];
    aptr[p] = xb + (size_t)(enc >> 1) * CDIM + sc8;
    bptr[p] = w1b + (size_t)e * DFF * CDIM + (size_t)(n0 + row) * CDIM + sc8;
  }

  f32x4 acc[8][4] = {};
  int wm = w >> 2, wn = w & 3;
  int ln = l & 15, kq = l >> 4;
  int rx = ln & 7;

  for (int k0 = 0; k0 < CDIM; k0 += BK) {
    __syncthreads();
#pragma unroll
    for (int p = 0; p < 4; p++) {
      gld_lds16(aptr[p] + k0, &As[p * 64 + w8l][dst8]);
      gld_lds16(bptr[p] + k0, &Bs[p * 64 + w8l][dst8]);
    }
    __syncthreads();
#pragma unroll
    for (int hh = 0; hh < 2; hh++) {
      int co = ((hh * 4 + kq) ^ rx) * 8;  // swizzled chunk for this k-half
      bf16x8 af[8], bfr[4];
#pragma unroll
      for (int j = 0; j < 4; j++)
        bfr[j] = *(bf16x8*)&Bs[wn * 64 + j * 16 + ln][co];
#pragma unroll
      for (int i = 0; i < 8; i++)
        af[i] = *(bf16x8*)&As[wm * 128 + i * 16 + ln][co];
#pragma unroll
      for (int i = 0; i < 8; i++)
#pragma unroll
        for (int j = 0; j < 4; j++)
          acc[i][j] = __builtin_amdgcn_mfma_f32_16x16x32_bf16(
              af[i], bfr[j], acc[i][j], 0, 0, 0);
    }
  }

  // epilogue: bias + exact gelu -> bf16 h
  float b1f[4];
#pragma unroll
  for (int j = 0; j < 4; j++)
    b1f[j] = b1[e * DFF + n0 + wn * 64 + j * 16 + ln];
#pragma unroll
  for (int i = 0; i < 8; i++) {
#pragma unroll
    for (int r = 0; r < 4; r++) {
      int mrow = wm * 128 + i * 16 + kq * 4 + r;
      if (m0 + mrow < count) {
        int enc = lp[m0 + mrow];
        bf16* hr = h + (size_t)enc * DFF + n0 + wn * 64 + ln;
#pragma unroll
        for (int j = 0; j < 4; j++) {
          float v = acc[i][j][r] + b1f[j];
          float g = 0.5f * v * (1.0f + erff(v * 0.70710678118654752f));
          hr[j * 16] = (bf16)g;
        }
      }
    }
  }
}

// ------- GEMM2: out[t] += wq[enc] * (h[enc] @ w2[e] + b2[e]) ----------------
__global__ __launch_bounds__(512, 2) void gemm2_kernel(
    const bf16* __restrict__ h, const bf16* __restrict__ w2b,
    const float* __restrict__ b2, const int* __restrict__ list,
    const unsigned int* __restrict__ cnt, const float* __restrict__ wq,
    float* __restrict__ out) {
  // grid = 4 x 32 x 8 = 1024 blocks; chunk = 128 per XCD
  int bid = blockIdx.x + 4 * (blockIdx.y + 32 * blockIdx.z);
  int wg = (bid & 7) * 128 + (bid >> 3);
  int n0 = (wg & 3) * BN;
  int mt = (wg >> 2) & 31;
  int e = wg >> 7;
  int count = (int)min(cnt[e], (unsigned)NTOK);
  int m0 = mt * BM;
  if (m0 >= count) return;

  __shared__ __align__(16) bf16 As[BM][BK];
  __shared__ __align__(16) bf16 Bs[BN][BK];

  int tid = threadIdx.x;
  int w = tid >> 6, l = tid & 63;
  int lhi = l >> 3, llo = l & 7;
  int w8l = w * 8 + lhi;
  int dst8 = llo * 8;
  int sc8 = (llo ^ lhi) * 8;

  const int* lp = list + e * NTOK;
  const bf16* aptr[4];
  const bf16* bptr[4];
#pragma unroll
  for (int p = 0; p < 4; p++) {
    int row = p * 64 + w8l;
    int enc = lp[min(m0 + row, count - 1)];
    aptr[p] = h + (size_t)enc * DFF + sc8;
    bptr[p] = w2b + (size_t)e * CDIM * DFF + (size_t)(n0 + row) * DFF + sc8;
  }

  f32x4 acc[8][4] = {};
  int wm = w >> 2, wn = w & 3;
  int ln = l & 15, kq = l >> 4;
  int rx = ln & 7;

  for (int k0 = 0; k0 < DFF; k0 += BK) {
    __syncthreads();
#pragma unroll
    for (int p = 0; p < 4; p++) {
      gld_lds16(aptr[p] + k0, &As[p * 64 + w8l][dst8]);
      gld_lds16(bptr[p] + k0, &Bs[p * 64 + w8l][dst8]);
    }
    __syncthreads();
#pragma unroll
    for (int hh = 0; hh < 2; hh++) {
      int co = ((hh * 4 + kq) ^ rx) * 8;
      bf16x8 af[8], bfr[4];
#pragma unroll
      for (int j = 0; j < 4; j++)
        bfr[j] = *(bf16x8*)&Bs[wn * 64 + j * 16 + ln][co];
#pragma unroll
      for (int i = 0; i < 8; i++)
        af[i] = *(bf16x8*)&As[wm * 128 + i * 16 + ln][co];
#pragma unroll
      for (int i = 0; i < 8; i++)
#pragma unroll
        for (int j = 0; j < 4; j++)
          acc[i][j] = __builtin_amdgcn_mfma_f32_16x16x32_bf16(
              af[i], bfr[j], acc[i][j], 0, 0, 0);
    }
  }

  float b2f[4];
#pragma unroll
  for (int j = 0; j < 4; j++)
    b2f[j] = b2[e * CDIM + n0 + wn * 64 + j * 16 + ln];
#pragma unroll
  for (int i = 0; i < 8; i++) {
#pragma unroll
    for (int r = 0; r < 4; r++) {
      int mrow = wm * 128 + i * 16 + kq * 4 + r;
      if (m0 + mrow < count) {
        int enc = lp[m0 + mrow];
        int t = enc >> 1;
        float wt = wq[enc];
        float* orow = out + (size_t)t * CDIM + n0 + wn * 64 + ln;
#pragma unroll
        for (int j = 0; j < 4; j++)
          atomicAdd(&orow[j * 16], wt * (acc[i][j][r] + b2f[j]));
      }
    }
  }
}

extern "C" void kernel_launch(void* const* d_in, const int* in_sizes, int n_in,
                              void* d_out, int out_size, void* d_ws,
                              size_t ws_size, hipStream_t stream) {
  const float* x = (const float*)d_in[0];
  const float* rw = (const float*)d_in[1];
  const float* rb = (const float*)d_in[2];
  const float* w1 = (const float*)d_in[3];
  const float* b1 = (const float*)d_in[4];
  const float* w2 = (const float*)d_in[5];
  const float* b2 = (const float*)d_in[6];
  float* out = (float*)d_out;

  char* ws = (char*)d_ws;
  size_t o = 0;
  auto carve = [&](size_t bytes) {
    void* p = ws + o;
    o = (o + bytes + 255) & ~(size_t)255;
    return p;
  };
  bf16* w1b = (bf16*)carve((size_t)EXP * DFF * CDIM * 2);   // 67 MB
  bf16* w2b = (bf16*)carve((size_t)EXP * DFF * CDIM * 2);   // 67 MB
  bf16* h = (bf16*)carve((size_t)2 * NTOK * DFF * 2);       // 134 MB
  bf16* xb = (bf16*)carve((size_t)NTOK * CDIM * 2);         // 17 MB
  int* list = (int*)carve((size_t)EXP * NTOK * 4);
  float* wq = (float*)carve((size_t)2 * NTOK * 4);
  unsigned int* cnt = (unsigned int*)carve(64);

  hipMemsetAsync(out, 0, (size_t)out_size * sizeof(float), stream);
  hipMemsetAsync(cnt, 0, 64, stream);

  convert_x<<<NTOK * CDIM / (256 * 8), 256, 0, stream>>>(x, xb);
  transpose_cvt<<<dim3(DFF / 32, CDIM / 32, EXP), 256, 0, stream>>>(w1, w1b,
                                                                    CDIM, DFF);
  transpose_cvt<<<dim3(CDIM / 32, DFF / 32, EXP), 256, 0, stream>>>(w2, w2b,
                                                                    DFF, CDIM);
  router_kernel<<<NTOK / 4, 256, 0, stream>>>(x, rw, rb, cnt, list, wq);
  gemm1_kernel<<<dim3(DFF / BN, NTOK / BM, EXP), 512, 0, stream>>>(
      xb, w1b, b1, list, cnt, h);
  gemm2_kernel<<<dim3(CDIM / BN, NTOK / BM, EXP), 512, 0, stream>>>(
      h, w2b, b2, list, cnt, wq, out);
}

// Round 3
// 1107.974 us; speedup vs baseline: 1.0845x; 1.0845x over previous
//
#include <hip/hip_runtime.h>
#include <math.h>

typedef __bf16 bf16;
typedef bf16 bf16x4 __attribute__((ext_vector_type(4)));
typedef bf16 bf16x8 __attribute__((ext_vector_type(8)));
typedef float f32x4 __attribute__((ext_vector_type(4)));

#define NTOK 8192      // B*T
#define CDIM 1024
#define EXP 8
#define DFF 4096
#define BM 256
#define BN 256
#define BK 64

__device__ __forceinline__ void gld_lds16(const bf16* g, bf16* l) {
  __builtin_amdgcn_global_load_lds(
      (const __attribute__((address_space(1))) unsigned int*)g,
      (__attribute__((address_space(3))) unsigned int*)l, 16, 0, 0);
}

// ---------------- x fp32 -> bf16 convert (one-shot) ----------------
__global__ __launch_bounds__(256) void convert_x(const float* __restrict__ in,
                                                 bf16* __restrict__ out) {
  int idx = (blockIdx.x * 256 + threadIdx.x) * 8;
  float4 a = *(const float4*)(in + idx);
  float4 b = *(const float4*)(in + idx + 4);
  bf16x8 v;
  v[0] = (bf16)a.x; v[1] = (bf16)a.y; v[2] = (bf16)a.z; v[3] = (bf16)a.w;
  v[4] = (bf16)b.x; v[5] = (bf16)b.y; v[6] = (bf16)b.z; v[7] = (bf16)b.w;
  *(bf16x8*)(out + idx) = v;
}

// ---------------- transpose + fp32->bf16 convert ----------------
// in: per-expert [R][Cin] fp32, out: per-expert [Cin][R] bf16
__global__ __launch_bounds__(256) void transpose_cvt(
    const float* __restrict__ in, bf16* __restrict__ out, int R, int Cin) {
  __shared__ float tile[32][33];
  int e = blockIdx.z;
  const float* ip = in + (size_t)e * R * Cin;
  bf16* op = out + (size_t)e * R * Cin;
  int c0 = blockIdx.x * 32, r0 = blockIdx.y * 32;
  int tx = threadIdx.x & 31, ty = threadIdx.x >> 5;  // ty in 0..7
#pragma unroll
  for (int i = 0; i < 4; i++)
    tile[ty + 8 * i][tx] = ip[(size_t)(r0 + ty + 8 * i) * Cin + c0 + tx];
  __syncthreads();
  int c = threadIdx.x >> 3, r4 = (threadIdx.x & 7) * 4;
  bf16x4 v;
  v[0] = (bf16)tile[r4][c];
  v[1] = (bf16)tile[r4 + 1][c];
  v[2] = (bf16)tile[r4 + 2][c];
  v[3] = (bf16)tile[r4 + 3][c];
  *(bf16x4*)&op[(size_t)(c0 + c) * R + r0 + r4] = v;
}

// ---------------- router: logits -> softmax -> top2 -> lists ----------------
__global__ __launch_bounds__(256) void router_kernel(
    const float* __restrict__ x, const float* __restrict__ rw,
    const float* __restrict__ rb, unsigned int* __restrict__ cnt,
    int* __restrict__ list, float* __restrict__ wq) {
  int wave = threadIdx.x >> 6, lane = threadIdx.x & 63;
  int t = blockIdx.x * 4 + wave;
  if (t >= NTOK) return;
  const float* xr = x + (size_t)t * CDIM;
  float acc[8] = {0.f, 0.f, 0.f, 0.f, 0.f, 0.f, 0.f, 0.f};
  for (int c = lane; c < CDIM; c += 64) {
    float xv = xr[c];
    const float4* rp = (const float4*)(rw + c * 8);
    float4 r0 = rp[0], r1 = rp[1];
    acc[0] += xv * r0.x; acc[1] += xv * r0.y;
    acc[2] += xv * r0.z; acc[3] += xv * r0.w;
    acc[4] += xv * r1.x; acc[5] += xv * r1.y;
    acc[6] += xv * r1.z; acc[7] += xv * r1.w;
  }
#pragma unroll
  for (int e = 0; e < 8; e++)
#pragma unroll
    for (int off = 32; off; off >>= 1) acc[e] += __shfl_down(acc[e], off);
  if (lane == 0) {
    float p[8], mx = -1e30f;
#pragma unroll
    for (int e = 0; e < 8; e++) { p[e] = acc[e] + rb[e]; mx = fmaxf(mx, p[e]); }
    float s = 0.f;
#pragma unroll
    for (int e = 0; e < 8; e++) { p[e] = expf(p[e] - mx); s += p[e]; }
    float inv = 1.0f / s;
#pragma unroll
    for (int e = 0; e < 8; e++) p[e] *= inv;
    int i1 = 0;
#pragma unroll
    for (int e = 1; e < 8; e++) if (p[e] > p[i1]) i1 = e;
    int i2 = (i1 == 0) ? 1 : 0;
#pragma unroll
    for (int e = 0; e < 8; e++) if (e != i1 && p[e] > p[i2]) i2 = e;
    unsigned s0 = atomicAdd(&cnt[i1], 1u);
    list[i1 * NTOK + s0] = t * 2;
    unsigned s1 = atomicAdd(&cnt[i2], 1u);
    list[i2 * NTOK + s1] = t * 2 + 1;
    wq[t * 2] = p[i1];
    wq[t * 2 + 1] = p[i2];
  }
}

// ---------------- GEMM1: h[enc] = gelu(xb[t] @ w1[e] + b1[e]) ----------------
// 256x256 tile, BK=64, 512 thr (8 waves 2Mx4N), chunk-XOR swizzled LDS,
// XCD-chunked block swizzle, 2-phase double-buffered staging (T3-min).
__global__ __launch_bounds__(512, 2) void gemm1_kernel(
    const bf16* __restrict__ xb, const bf16* __restrict__ w1b,
    const float* __restrict__ b1, const int* __restrict__ list,
    const unsigned int* __restrict__ cnt, bf16* __restrict__ h) {
  // grid = 16 x 32 x 8 = 4096 blocks; chunk = 512 per XCD
  int bid = blockIdx.x + 16 * (blockIdx.y + 32 * blockIdx.z);
  int wg = (bid & 7) * 512 + (bid >> 3);
  int n0 = (wg & 15) * BN;
  int mt = (wg >> 4) & 31;
  int e = wg >> 9;
  int count = (int)min(cnt[e], (unsigned)NTOK);
  int m0 = mt * BM;
  if (m0 >= count) return;

  __shared__ __align__(16) bf16 As[2][BM][BK];  // 64 KB
  __shared__ __align__(16) bf16 Bs[2][BM][BK];  // 64 KB

  int tid = threadIdx.x;
  int w = tid >> 6, l = tid & 63;
  int lhi = l >> 3, llo = l & 7;
  int w8l = w * 8 + lhi;          // row within 64-row pass group
  int dst8 = llo * 8;             // linear LDS dest col (elems)
  int sc8 = (llo ^ lhi) * 8;      // pre-swizzled global source col (elems)

  const int* lp = list + e * NTOK;
  const bf16* aptr[4];
  const bf16* bptr[4];
#pragma unroll
  for (int p = 0; p < 4; p++) {
    int row = p * 64 + w8l;
    int enc = lp[min(m0 + row, count - 1)];
    aptr[p] = xb + (size_t)(enc >> 1) * CDIM + sc8;
    bptr[p] = w1b + (size_t)e * DFF * CDIM + (size_t)(n0 + row) * CDIM + sc8;
  }

  f32x4 acc[8][4] = {};
  int wm = w >> 2, wn = w & 3;
  int ln = l & 15, kq = l >> 4;
  int rx = ln & 7;

  // prologue: stage tile 0 into buf 0
#pragma unroll
  for (int p = 0; p < 4; p++) {
    gld_lds16(aptr[p], &As[0][p * 64 + w8l][dst8]);
    gld_lds16(bptr[p], &Bs[0][p * 64 + w8l][dst8]);
  }
  __syncthreads();  // implicit vmcnt(0) drain

  const int NT = CDIM / BK;  // 16
  int cur = 0;
  for (int t = 0; t < NT; ++t) {
    if (t + 1 < NT) {  // issue next-tile prefetch BEFORE compute
      int k0 = (t + 1) * BK;
#pragma unroll
      for (int p = 0; p < 4; p++) {
        gld_lds16(aptr[p] + k0, &As[cur ^ 1][p * 64 + w8l][dst8]);
        gld_lds16(bptr[p] + k0, &Bs[cur ^ 1][p * 64 + w8l][dst8]);
      }
    }
    bf16(*Asc)[BK] = As[cur];
    bf16(*Bsc)[BK] = Bs[cur];
#pragma unroll
    for (int hh = 0; hh < 2; hh++) {
      int co = ((hh * 4 + kq) ^ rx) * 8;  // swizzled chunk for this k-half
      bf16x8 af[8], bfr[4];
#pragma unroll
      for (int j = 0; j < 4; j++)
        bfr[j] = *(bf16x8*)&Bsc[wn * 64 + j * 16 + ln][co];
#pragma unroll
      for (int i = 0; i < 8; i++)
        af[i] = *(bf16x8*)&Asc[wm * 128 + i * 16 + ln][co];
#pragma unroll
      for (int i = 0; i < 8; i++)
#pragma unroll
        for (int j = 0; j < 4; j++)
          acc[i][j] = __builtin_amdgcn_mfma_f32_16x16x32_bf16(
              af[i], bfr[j], acc[i][j], 0, 0, 0);
    }
    __syncthreads();  // vmcnt(0): prefetch (issued pre-compute) now complete
    cur ^= 1;
  }

  // epilogue: bias + exact gelu -> bf16 h
  float b1f[4];
#pragma unroll
  for (int j = 0; j < 4; j++)
    b1f[j] = b1[e * DFF + n0 + wn * 64 + j * 16 + ln];
#pragma unroll
  for (int i = 0; i < 8; i++) {
#pragma unroll
    for (int r = 0; r < 4; r++) {
      int mrow = wm * 128 + i * 16 + kq * 4 + r;
      if (m0 + mrow < count) {
        int enc = lp[m0 + mrow];
        bf16* hr = h + (size_t)enc * DFF + n0 + wn * 64 + ln;
#pragma unroll
        for (int j = 0; j < 4; j++) {
          float v = acc[i][j][r] + b1f[j];
          float g = 0.5f * v * (1.0f + erff(v * 0.70710678118654752f));
          hr[j * 16] = (bf16)g;
        }
      }
    }
  }
}

// ------- GEMM2: y[enc] = wq[enc] * (h[enc] @ w2[e] + b2[e])  (plain stores) --
__global__ __launch_bounds__(512, 2) void gemm2_kernel(
    const bf16* __restrict__ h, const bf16* __restrict__ w2b,
    const float* __restrict__ b2, const int* __restrict__ list,
    const unsigned int* __restrict__ cnt, const float* __restrict__ wq,
    float* __restrict__ y) {
  // grid = 4 x 32 x 8 = 1024 blocks; chunk = 128 per XCD
  int bid = blockIdx.x + 4 * (blockIdx.y + 32 * blockIdx.z);
  int wg = (bid & 7) * 128 + (bid >> 3);
  int n0 = (wg & 3) * BN;
  int mt = (wg >> 2) & 31;
  int e = wg >> 7;
  int count = (int)min(cnt[e], (unsigned)NTOK);
  int m0 = mt * BM;
  if (m0 >= count) return;

  __shared__ __align__(16) bf16 As[2][BM][BK];
  __shared__ __align__(16) bf16 Bs[2][BM][BK];

  int tid = threadIdx.x;
  int w = tid >> 6, l = tid & 63;
  int lhi = l >> 3, llo = l & 7;
  int w8l = w * 8 + lhi;
  int dst8 = llo * 8;
  int sc8 = (llo ^ lhi) * 8;

  const int* lp = list + e * NTOK;
  const bf16* aptr[4];
  const bf16* bptr[4];
#pragma unroll
  for (int p = 0; p < 4; p++) {
    int row = p * 64 + w8l;
    int enc = lp[min(m0 + row, count - 1)];
    aptr[p] = h + (size_t)enc * DFF + sc8;
    bptr[p] = w2b + (size_t)e * CDIM * DFF + (size_t)(n0 + row) * DFF + sc8;
  }

  f32x4 acc[8][4] = {};
  int wm = w >> 2, wn = w & 3;
  int ln = l & 15, kq = l >> 4;
  int rx = ln & 7;

#pragma unroll
  for (int p = 0; p < 4; p++) {
    gld_lds16(aptr[p], &As[0][p * 64 + w8l][dst8]);
    gld_lds16(bptr[p], &Bs[0][p * 64 + w8l][dst8]);
  }
  __syncthreads();

  const int NT = DFF / BK;  // 64
  int cur = 0;
  for (int t = 0; t < NT; ++t) {
    if (t + 1 < NT) {
      int k0 = (t + 1) * BK;
#pragma unroll
      for (int p = 0; p < 4; p++) {
        gld_lds16(aptr[p] + k0, &As[cur ^ 1][p * 64 + w8l][dst8]);
        gld_lds16(bptr[p] + k0, &Bs[cur ^ 1][p * 64 + w8l][dst8]);
      }
    }
    bf16(*Asc)[BK] = As[cur];
    bf16(*Bsc)[BK] = Bs[cur];
#pragma unroll
    for (int hh = 0; hh < 2; hh++) {
      int co = ((hh * 4 + kq) ^ rx) * 8;
      bf16x8 af[8], bfr[4];
#pragma unroll
      for (int j = 0; j < 4; j++)
        bfr[j] = *(bf16x8*)&Bsc[wn * 64 + j * 16 + ln][co];
#pragma unroll
      for (int i = 0; i < 8; i++)
        af[i] = *(bf16x8*)&Asc[wm * 128 + i * 16 + ln][co];
#pragma unroll
      for (int i = 0; i < 8; i++)
#pragma unroll
        for (int j = 0; j < 4; j++)
          acc[i][j] = __builtin_amdgcn_mfma_f32_16x16x32_bf16(
              af[i], bfr[j], acc[i][j], 0, 0, 0);
    }
    __syncthreads();
    cur ^= 1;
  }

  float b2f[4];
#pragma unroll
  for (int j = 0; j < 4; j++)
    b2f[j] = b2[e * CDIM + n0 + wn * 64 + j * 16 + ln];
#pragma unroll
  for (int i = 0; i < 8; i++) {
#pragma unroll
    for (int r = 0; r < 4; r++) {
      int mrow = wm * 128 + i * 16 + kq * 4 + r;
      if (m0 + mrow < count) {
        int enc = lp[m0 + mrow];
        float wt = wq[enc];
        float* yr = y + (size_t)enc * CDIM + n0 + wn * 64 + ln;
#pragma unroll
        for (int j = 0; j < 4; j++)
          yr[j * 16] = wt * (acc[i][j][r] + b2f[j]);
      }
    }
  }
}

// ---------- combine: out[t] = y[2t] + y[2t+1] (every enc written once) ------
__global__ __launch_bounds__(256) void combine_kernel(
    const float* __restrict__ y, float* __restrict__ out) {
  int idx = (blockIdx.x * 256 + threadIdx.x) * 4;
  int t = idx >> 10;          // token (CDIM=1024)
  int c = idx & 1023;
  const float* y0 = y + ((size_t)(t * 2) << 10) + c;
  float4 a = *(const float4*)y0;
  float4 b = *(const float4*)(y0 + CDIM);
  float4 r;
  r.x = a.x + b.x; r.y = a.y + b.y; r.z = a.z + b.z; r.w = a.w + b.w;
  *(float4*)(out + idx) = r;
}

extern "C" void kernel_launch(void* const* d_in, const int* in_sizes, int n_in,
                              void* d_out, int out_size, void* d_ws,
                              size_t ws_size, hipStream_t stream) {
  const float* x = (const float*)d_in[0];
  const float* rw = (const float*)d_in[1];
  const float* rb = (const float*)d_in[2];
  const float* w1 = (const float*)d_in[3];
  const float* b1 = (const float*)d_in[4];
  const float* w2 = (const float*)d_in[5];
  const float* b2 = (const float*)d_in[6];
  float* out = (float*)d_out;

  char* ws = (char*)d_ws;
  size_t o = 0;
  auto carve = [&](size_t bytes) {
    void* p = ws + o;
    o = (o + bytes + 255) & ~(size_t)255;
    return p;
  };
  bf16* w1b = (bf16*)carve((size_t)EXP * DFF * CDIM * 2);   // 67 MB
  bf16* w2b = (bf16*)carve((size_t)EXP * DFF * CDIM * 2);   // 67 MB
  bf16* h = (bf16*)carve((size_t)2 * NTOK * DFF * 2);       // 134 MB
  bf16* xb = (bf16*)carve((size_t)NTOK * CDIM * 2);         // 17 MB
  int* list = (int*)carve((size_t)EXP * NTOK * 4);
  float* wq = (float*)carve((size_t)2 * NTOK * 4);
  unsigned int* cnt = (unsigned int*)carve(64);
  // y aliases w1b: w1b (67,108,864 B) is dead after gemm1; y needs exactly
  // 2*NTOK*CDIM*4 = 67,108,864 B. Rewritten by transpose_cvt next launch.
  float* y = (float*)w1b;

  hipMemsetAsync(cnt, 0, 64, stream);

  convert_x<<<NTOK * CDIM / (256 * 8), 256, 0, stream>>>(x, xb);
  transpose_cvt<<<dim3(DFF / 32, CDIM / 32, EXP), 256, 0, stream>>>(w1, w1b,
                                                                    CDIM, DFF);
  transpose_cvt<<<dim3(CDIM / 32, DFF / 32, EXP), 256, 0, stream>>>(w2, w2b,
                                                                    DFF, CDIM);
  router_kernel<<<NTOK / 4, 256, 0, stream>>>(x, rw, rb, cnt, list, wq);
  gemm1_kernel<<<dim3(DFF / BN, NTOK / BM, EXP), 512, 0, stream>>>(
      xb, w1b, b1, list, cnt, h);
  gemm2_kernel<<<dim3(CDIM / BN, NTOK / BM, EXP), 512, 0, stream>>>(
      h, w2b, b2, list, cnt, wq, y);
  combine_kernel<<<NTOK * CDIM / (256 * 4), 256, 0, stream>>>(y, out);
}

// Round 4
// 1085.630 us; speedup vs baseline: 1.1068x; 1.0206x over previous
//
#include <hip/hip_runtime.h>
#include <math.h>

typedef __bf16 bf16;
typedef bf16 bf16x4 __attribute__((ext_vector_type(4)));
typedef bf16 bf16x8 __attribute__((ext_vector_type(8)));
typedef float f32x4 __attribute__((ext_vector_type(4)));

#define NTOK 8192      // B*T
#define CDIM 1024
#define EXP 8
#define DFF 4096
#define BM 256
#define BN 256
#define BK 64
#define HALF_E 8192    // elems per (buf,ks) half: 256 rows x 32 cols

__device__ __forceinline__ void gld_lds16(const bf16* g, bf16* l) {
  __builtin_amdgcn_global_load_lds(
      (const __attribute__((address_space(1))) unsigned int*)g,
      (__attribute__((address_space(3))) unsigned int*)l, 16, 0, 0);
}

// ---------------- x fp32 -> bf16 convert (one-shot) ----------------
__global__ __launch_bounds__(256) void convert_x(const float* __restrict__ in,
                                                 bf16* __restrict__ out) {
  int idx = (blockIdx.x * 256 + threadIdx.x) * 8;
  float4 a = *(const float4*)(in + idx);
  float4 b = *(const float4*)(in + idx + 4);
  bf16x8 v;
  v[0] = (bf16)a.x; v[1] = (bf16)a.y; v[2] = (bf16)a.z; v[3] = (bf16)a.w;
  v[4] = (bf16)b.x; v[5] = (bf16)b.y; v[6] = (bf16)b.z; v[7] = (bf16)b.w;
  *(bf16x8*)(out + idx) = v;
}

// ---------------- transpose + fp32->bf16 convert (coalesced 16B stores) -----
// in: per-expert [R][Cin] fp32, out: per-expert [Cin][R] bf16
// tile: 64 rows (R-dim) x 32 cols (Cin-dim)
__global__ __launch_bounds__(256) void transpose_cvt(
    const float* __restrict__ in, bf16* __restrict__ out, int R, int Cin) {
  __shared__ float tile[64][33];
  int e = blockIdx.z;
  const float* ip = in + (size_t)e * R * Cin;
  bf16* op = out + (size_t)e * R * Cin;
  int c0 = blockIdx.x * 32, r0 = blockIdx.y * 64;
  int tr = threadIdx.x >> 5, tc = threadIdx.x & 31;  // tr 0..7
#pragma unroll
  for (int i = 0; i < 8; i++)
    tile[tr + 8 * i][tc] = ip[(size_t)(r0 + tr + 8 * i) * Cin + c0 + tc];
  __syncthreads();
  int oc = threadIdx.x >> 3;        // 0..31: cin within tile
  int orr = (threadIdx.x & 7) * 8;  // 0..56: r offset
  bf16x8 v;
#pragma unroll
  for (int k = 0; k < 8; k++) v[k] = (bf16)tile[orr + k][oc];
  *(bf16x8*)&op[(size_t)(c0 + oc) * R + r0 + orr] = v;
}

// ---------------- router: logits -> softmax -> top2 -> lists ----------------
__global__ __launch_bounds__(256) void router_kernel(
    const float* __restrict__ x, const float* __restrict__ rw,
    const float* __restrict__ rb, unsigned int* __restrict__ cnt,
    int* __restrict__ list, float* __restrict__ wq) {
  int wave = threadIdx.x >> 6, lane = threadIdx.x & 63;
  int t = blockIdx.x * 4 + wave;
  if (t >= NTOK) return;
  const float* xr = x + (size_t)t * CDIM;
  float acc[8] = {0.f, 0.f, 0.f, 0.f, 0.f, 0.f, 0.f, 0.f};
  for (int c = lane; c < CDIM; c += 64) {
    float xv = xr[c];
    const float4* rp = (const float4*)(rw + c * 8);
    float4 r0 = rp[0], r1 = rp[1];
    acc[0] += xv * r0.x; acc[1] += xv * r0.y;
    acc[2] += xv * r0.z; acc[3] += xv * r0.w;
    acc[4] += xv * r1.x; acc[5] += xv * r1.y;
    acc[6] += xv * r1.z; acc[7] += xv * r1.w;
  }
#pragma unroll
  for (int e = 0; e < 8; e++)
#pragma unroll
    for (int off = 32; off; off >>= 1) acc[e] += __shfl_down(acc[e], off);
  if (lane == 0) {
    float p[8], mx = -1e30f;
#pragma unroll
    for (int e = 0; e < 8; e++) { p[e] = acc[e] + rb[e]; mx = fmaxf(mx, p[e]); }
    float s = 0.f;
#pragma unroll
    for (int e = 0; e < 8; e++) { p[e] = expf(p[e] - mx); s += p[e]; }
    float inv = 1.0f / s;
#pragma unroll
    for (int e = 0; e < 8; e++) p[e] *= inv;
    int i1 = 0;
#pragma unroll
    for (int e = 1; e < 8; e++) if (p[e] > p[i1]) i1 = e;
    int i2 = (i1 == 0) ? 1 : 0;
#pragma unroll
    for (int e = 0; e < 8; e++) if (e != i1 && p[e] > p[i2]) i2 = e;
    unsigned s0 = atomicAdd(&cnt[i1], 1u);
    list[i1 * NTOK + s0] = t * 2;
    unsigned s1 = atomicAdd(&cnt[i2], 1u);
    list[i2 * NTOK + s1] = t * 2 + 1;
    wq[t * 2] = p[i1];
    wq[t * 2 + 1] = p[i2];
  }
}

// ---- shared GEMM core: 256x256 tile, BK=64, K-half progressive 4-phase ----
// LDS halves: [buf][ks][256][32] bf16. Stage sigma = phase+6, vmcnt(6) at
// q=0,2 (ledger-verified); tail drains 6 -> 2 -> 0.
__device__ __forceinline__ void ld_afrag(const bf16* base, int aoff, int ih,
                                         bf16x8 (&af)[4]) {
#pragma unroll
  for (int i = 0; i < 4; i++)
    af[i] = *(const bf16x8*)&base[aoff + (ih * 64 + i * 16) * 32];
}
__device__ __forceinline__ void ld_bfrag(const bf16* base, int boff,
                                         bf16x8 (&bfr)[4]) {
#pragma unroll
  for (int j = 0; j < 4; j++)
    bfr[j] = *(const bf16x8*)&base[boff + j * 16 * 32];
}

#define MFMA16(IH)                                                        \
  do {                                                                    \
    __builtin_amdgcn_s_setprio(1);                                        \
    _Pragma("unroll") for (int i = 0; i < 4; i++)                         \
        _Pragma("unroll") for (int j = 0; j < 4; j++) acc[(IH)*4 + i][j] = \
            __builtin_amdgcn_mfma_f32_16x16x32_bf16(af[i], bfr[j],        \
                                                    acc[(IH)*4 + i][j],   \
                                                    0, 0, 0);             \
    __builtin_amdgcn_s_setprio(0);                                        \
  } while (0)

#define STAGE(P1, P2, LDSBUF, TK, KS)                                     \
  do {                                                                    \
    int _k = (TK) * BK + (KS)*32;                                         \
    bf16* _d = &LDSBUF[(((((TK)&1) << 1) | (KS)) * HALF_E) + tid * 8];    \
    gld_lds16((P1) + _k, _d);                                             \
    gld_lds16((P2) + _k, _d + 4096);                                      \
  } while (0)

template <int NT>
__device__ __forceinline__ void gemm_core(
    const bf16* aRow1, const bf16* aRow2, const bf16* bRow1, const bf16* bRow2,
    bf16* Asf, bf16* Bsf, int tid, f32x4 (&acc)[8][4]) {
  int w = tid >> 6, l = tid & 63;
  int ln = l & 15, kq = l >> 4;
  int wm = w >> 2, wn = w & 3;
  int rc8 = (kq ^ ((ln >> 1) & 3)) * 8;       // swizzled read chunk
  int aoff = (wm * 128 + ln) * 32 + rc8;
  int boff = (wn * 64 + ln) * 32 + rc8;

  bf16x8 af[4], bfr[4];

  // prologue: sigma 0..5 (tile0 all, tile1 ks0), then guarantee sigma<=1
  STAGE(aRow1, aRow2, Asf, 0, 0);
  STAGE(bRow1, bRow2, Bsf, 0, 0);
  STAGE(aRow1, aRow2, Asf, 0, 1);
  STAGE(bRow1, bRow2, Bsf, 0, 1);
  STAGE(aRow1, aRow2, Asf, 1, 0);
  STAGE(bRow1, bRow2, Bsf, 1, 0);
  asm volatile("s_waitcnt vmcnt(8)" ::: "memory");
  __builtin_amdgcn_s_barrier();

  for (int t = 0; t < NT; ++t) {
    int sel = (t & 1) << 1;
    const bf16* A0 = &Asf[sel * HALF_E];
    const bf16* A1 = &Asf[(sel | 1) * HALF_E];
    const bf16* B0 = &Bsf[sel * HALF_E];
    const bf16* B1 = &Bsf[(sel | 1) * HALF_E];

    // ---- q0: (ks0, ih0) ----
    ld_bfrag(B0, boff, bfr);
    ld_afrag(A0, aoff, 0, af);
    if (t + 1 < NT) STAGE(aRow1, aRow2, Asf, t + 1, 1);   // sigma = 4t+6
    if (t < NT - 1) asm volatile("s_waitcnt vmcnt(6)" ::: "memory");
    else            asm volatile("s_waitcnt vmcnt(0)" ::: "memory");
    __builtin_amdgcn_s_barrier();
    asm volatile("s_waitcnt lgkmcnt(0)" ::: "memory");
    __builtin_amdgcn_sched_barrier(0);
    MFMA16(0);
    __builtin_amdgcn_s_barrier();

    // ---- q1: (ks0, ih1), reuse bfr ----
    ld_afrag(A0, aoff, 1, af);
    if (t + 1 < NT) STAGE(bRow1, bRow2, Bsf, t + 1, 1);   // sigma = 4t+7
    __builtin_amdgcn_s_barrier();
    asm volatile("s_waitcnt lgkmcnt(0)" ::: "memory");
    __builtin_amdgcn_sched_barrier(0);
    MFMA16(1);
    __builtin_amdgcn_s_barrier();

    // ---- q2: (ks1, ih0) ----
    ld_bfrag(B1, boff, bfr);
    ld_afrag(A1, aoff, 0, af);
    if (t + 2 < NT) STAGE(aRow1, aRow2, Asf, t + 2, 0);   // sigma = 4t+8
    if (t < NT - 2)       asm volatile("s_waitcnt vmcnt(6)" ::: "memory");
    else if (t == NT - 2) asm volatile("s_waitcnt vmcnt(2)" ::: "memory");
    else                  asm volatile("s_waitcnt vmcnt(0)" ::: "memory");
    __builtin_amdgcn_s_barrier();
    asm volatile("s_waitcnt lgkmcnt(0)" ::: "memory");
    __builtin_amdgcn_sched_barrier(0);
    MFMA16(0);
    __builtin_amdgcn_s_barrier();

    // ---- q3: (ks1, ih1), reuse bfr ----
    ld_afrag(A1, aoff, 1, af);
    if (t + 2 < NT) STAGE(bRow1, bRow2, Bsf, t + 2, 0);   // sigma = 4t+9
    __builtin_amdgcn_s_barrier();
    asm volatile("s_waitcnt lgkmcnt(0)" ::: "memory");
    __builtin_amdgcn_sched_barrier(0);
    MFMA16(1);
    __builtin_amdgcn_s_barrier();
  }
}

// ---------------- GEMM1: h[enc] = gelu(xb[t] @ w1[e] + b1[e]) ----------------
__global__ __launch_bounds__(512, 2) void gemm1_kernel(
    const bf16* __restrict__ xb, const bf16* __restrict__ w1b,
    const float* __restrict__ b1, const int* __restrict__ list,
    const unsigned int* __restrict__ cnt, bf16* __restrict__ h) {
  // grid = 16 x 32 x 8 = 4096 blocks; XCD-chunked swizzle (4096 % 8 == 0)
  int bid = blockIdx.x + 16 * (blockIdx.y + 32 * blockIdx.z);
  int wg = (bid & 7) * 512 + (bid >> 3);
  int n0 = (wg & 15) * BN;
  int mt = (wg >> 4) & 31;
  int e = wg >> 9;
  int count = (int)min(cnt[e], (unsigned)NTOK);
  int m0 = mt * BM;
  if (m0 >= count) return;

  __shared__ __align__(16) bf16 Asf[4 * HALF_E];  // 64 KB
  __shared__ __align__(16) bf16 Bsf[4 * HALF_E];  // 64 KB

  int tid = threadIdx.x;
  int row1 = tid >> 2;                        // 0..127
  int cx8 = ((tid & 3) ^ ((tid >> 3) & 3)) * 8;  // pre-swizzled source col

  const int* lp = list + e * NTOK;
  int encA1 = lp[min(m0 + row1, count - 1)];
  int encA2 = lp[min(m0 + row1 + 128, count - 1)];
  const bf16* aRow1 = xb + (size_t)(encA1 >> 1) * CDIM + cx8;
  const bf16* aRow2 = xb + (size_t)(encA2 >> 1) * CDIM + cx8;
  const bf16* bRow1 =
      w1b + (size_t)e * DFF * CDIM + (size_t)(n0 + row1) * CDIM + cx8;
  const bf16* bRow2 = bRow1 + (size_t)128 * CDIM;

  f32x4 acc[8][4] = {};
  gemm_core<CDIM / BK>(aRow1, aRow2, bRow1, bRow2, Asf, Bsf, tid, acc);

  int w = tid >> 6, l = tid & 63;
  int ln = l & 15, kq = l >> 4;
  int wm = w >> 2, wn = w & 3;
  // epilogue: bias + exact gelu -> bf16 h
  float b1f[4];
#pragma unroll
  for (int j = 0; j < 4; j++)
    b1f[j] = b1[e * DFF + n0 + wn * 64 + j * 16 + ln];
#pragma unroll
  for (int i = 0; i < 8; i++) {
#pragma unroll
    for (int r = 0; r < 4; r++) {
      int mrow = wm * 128 + i * 16 + kq * 4 + r;
      if (m0 + mrow < count) {
        int enc = lp[m0 + mrow];
        bf16* hr = h + (size_t)enc * DFF + n0 + wn * 64 + ln;
#pragma unroll
        for (int j = 0; j < 4; j++) {
          float v = acc[i][j][r] + b1f[j];
          float g = 0.5f * v * (1.0f + erff(v * 0.70710678118654752f));
          hr[j * 16] = (bf16)g;
        }
      }
    }
  }
}

// ------- GEMM2: y[enc] = wq[enc] * (h[enc] @ w2[e] + b2[e]) (plain stores) --
__global__ __launch_bounds__(512, 2) void gemm2_kernel(
    const bf16* __restrict__ h, const bf16* __restrict__ w2b,
    const float* __restrict__ b2, const int* __restrict__ list,
    const unsigned int* __restrict__ cnt, const float* __restrict__ wq,
    float* __restrict__ y) {
  // grid = 4 x 32 x 8 = 1024 blocks; XCD-chunked swizzle
  int bid = blockIdx.x + 4 * (blockIdx.y + 32 * blockIdx.z);
  int wg = (bid & 7) * 128 + (bid >> 3);
  int n0 = (wg & 3) * BN;
  int mt = (wg >> 2) & 31;
  int e = wg >> 7;
  int count = (int)min(cnt[e], (unsigned)NTOK);
  int m0 = mt * BM;
  if (m0 >= count) return;

  __shared__ __align__(16) bf16 Asf[4 * HALF_E];
  __shared__ __align__(16) bf16 Bsf[4 * HALF_E];

  int tid = threadIdx.x;
  int row1 = tid >> 2;
  int cx8 = ((tid & 3) ^ ((tid >> 3) & 3)) * 8;

  const int* lp = list + e * NTOK;
  int encA1 = lp[min(m0 + row1, count - 1)];
  int encA2 = lp[min(m0 + row1 + 128, count - 1)];
  const bf16* aRow1 = h + (size_t)encA1 * DFF + cx8;
  const bf16* aRow2 = h + (size_t)encA2 * DFF + cx8;
  const bf16* bRow1 =
      w2b + (size_t)e * CDIM * DFF + (size_t)(n0 + row1) * DFF + cx8;
  const bf16* bRow2 = bRow1 + (size_t)128 * DFF;

  f32x4 acc[8][4] = {};
  gemm_core<DFF / BK>(aRow1, aRow2, bRow1, bRow2, Asf, Bsf, tid, acc);

  int w = tid >> 6, l = tid & 63;
  int ln = l & 15, kq = l >> 4;
  int wm = w >> 2, wn = w & 3;
  float b2f[4];
#pragma unroll
  for (int j = 0; j < 4; j++)
    b2f[j] = b2[e * CDIM + n0 + wn * 64 + j * 16 + ln];
#pragma unroll
  for (int i = 0; i < 8; i++) {
#pragma unroll
    for (int r = 0; r < 4; r++) {
      int mrow = wm * 128 + i * 16 + kq * 4 + r;
      if (m0 + mrow < count) {
        int enc = lp[m0 + mrow];
        float wt = wq[enc];
        float* yr = y + (size_t)enc * CDIM + n0 + wn * 64 + ln;
#pragma unroll
        for (int j = 0; j < 4; j++)
          yr[j * 16] = wt * (acc[i][j][r] + b2f[j]);
      }
    }
  }
}

// ---------- combine: out[t] = y[2t] + y[2t+1] (every enc written once) ------
__global__ __launch_bounds__(256) void combine_kernel(
    const float* __restrict__ y, float* __restrict__ out) {
  int idx = (blockIdx.x * 256 + threadIdx.x) * 4;
  int t = idx >> 10;          // token (CDIM=1024)
  int c = idx & 1023;
  const float* y0 = y + ((size_t)(t * 2) << 10) + c;
  float4 a = *(const float4*)y0;
  float4 b = *(const float4*)(y0 + CDIM);
  float4 r;
  r.x = a.x + b.x; r.y = a.y + b.y; r.z = a.z + b.z; r.w = a.w + b.w;
  *(float4*)(out + idx) = r;
}

extern "C" void kernel_launch(void* const* d_in, const int* in_sizes, int n_in,
                              void* d_out, int out_size, void* d_ws,
                              size_t ws_size, hipStream_t stream) {
  const float* x = (const float*)d_in[0];
  const float* rw = (const float*)d_in[1];
  const float* rb = (const float*)d_in[2];
  const float* w1 = (const float*)d_in[3];
  const float* b1 = (const float*)d_in[4];
  const float* w2 = (const float*)d_in[5];
  const float* b2 = (const float*)d_in[6];
  float* out = (float*)d_out;

  char* ws = (char*)d_ws;
  size_t o = 0;
  auto carve = [&](size_t bytes) {
    void* p = ws + o;
    o = (o + bytes + 255) & ~(size_t)255;
    return p;
  };
  bf16* w1b = (bf16*)carve((size_t)EXP * DFF * CDIM * 2);   // 67 MB
  bf16* w2b = (bf16*)carve((size_t)EXP * DFF * CDIM * 2);   // 67 MB
  bf16* h = (bf16*)carve((size_t)2 * NTOK * DFF * 2);       // 134 MB
  bf16* xb = (bf16*)carve((size_t)NTOK * CDIM * 2);         // 17 MB
  int* list = (int*)carve((size_t)EXP * NTOK * 4);
  float* wq = (float*)carve((size_t)2 * NTOK * 4);
  unsigned int* cnt = (unsigned int*)carve(64);
  // y aliases w1b: w1b (67,108,864 B) dead after gemm1; y needs exactly
  // 2*NTOK*CDIM*4 = 67,108,864 B.
  float* y = (float*)w1b;

  hipMemsetAsync(cnt, 0, 64, stream);

  convert_x<<<NTOK * CDIM / (256 * 8), 256, 0, stream>>>(x, xb);
  // w1 [E][C][DFF] -> w1b [E][DFF][C]; w2 [E][DFF][C] -> w2b [E][C][DFF]
  transpose_cvt<<<dim3(DFF / 32, CDIM / 64, EXP), 256, 0, stream>>>(w1, w1b,
                                                                    CDIM, DFF);
  transpose_cvt<<<dim3(CDIM / 32, DFF / 64, EXP), 256, 0, stream>>>(w2, w2b,
                                                                    DFF, CDIM);
  router_kernel<<<NTOK / 4, 256, 0, stream>>>(x, rw, rb, cnt, list, wq);
  gemm1_kernel<<<dim3(DFF / BN, NTOK / BM, EXP), 512, 0, stream>>>(
      xb, w1b, b1, list, cnt, h);
  gemm2_kernel<<<dim3(CDIM / BN, NTOK / BM, EXP), 512, 0, stream>>>(
      h, w2b, b2, list, cnt, wq, y);
  combine_kernel<<<NTOK * CDIM / (256 * 4), 256, 0, stream>>>(y, out);
}

// Round 5
// 986.448 us; speedup vs baseline: 1.2181x; 1.1005x over previous
//
#include <hip/hip_runtime.h>
#include <math.h>

typedef __bf16 bf16;
typedef bf16 bf16x4 __attribute__((ext_vector_type(4)));
typedef bf16 bf16x8 __attribute__((ext_vector_type(8)));
typedef float f32x4 __attribute__((ext_vector_type(4)));

#define NTOK 8192      // B*T
#define CDIM 1024
#define EXP 8
#define DFF 4096
#define BM 256
#define BN 128
#define BK 32

__device__ __forceinline__ void gld_lds16(const bf16* g, bf16* l) {
  __builtin_amdgcn_global_load_lds(
      (const __attribute__((address_space(1))) unsigned int*)g,
      (__attribute__((address_space(3))) unsigned int*)l, 16, 0, 0);
}

// ---------------- x fp32 -> bf16 convert (one-shot) ----------------
__global__ __launch_bounds__(256) void convert_x(const float* __restrict__ in,
                                                 bf16* __restrict__ out) {
  int idx = (blockIdx.x * 256 + threadIdx.x) * 8;
  float4 a = *(const float4*)(in + idx);
  float4 b = *(const float4*)(in + idx + 4);
  bf16x8 v;
  v[0] = (bf16)a.x; v[1] = (bf16)a.y; v[2] = (bf16)a.z; v[3] = (bf16)a.w;
  v[4] = (bf16)b.x; v[5] = (bf16)b.y; v[6] = (bf16)b.z; v[7] = (bf16)b.w;
  *(bf16x8*)(out + idx) = v;
}

// ---------------- transpose + fp32->bf16 convert (coalesced 16B stores) -----
__global__ __launch_bounds__(256) void transpose_cvt(
    const float* __restrict__ in, bf16* __restrict__ out, int R, int Cin) {
  __shared__ float tile[64][33];
  int e = blockIdx.z;
  const float* ip = in + (size_t)e * R * Cin;
  bf16* op = out + (size_t)e * R * Cin;
  int c0 = blockIdx.x * 32, r0 = blockIdx.y * 64;
  int tr = threadIdx.x >> 5, tc = threadIdx.x & 31;  // tr 0..7
#pragma unroll
  for (int i = 0; i < 8; i++)
    tile[tr + 8 * i][tc] = ip[(size_t)(r0 + tr + 8 * i) * Cin + c0 + tc];
  __syncthreads();
  int oc = threadIdx.x >> 3;        // 0..31: cin within tile
  int orr = (threadIdx.x & 7) * 8;  // 0..56: r offset
  bf16x8 v;
#pragma unroll
  for (int k = 0; k < 8; k++) v[k] = (bf16)tile[orr + k][oc];
  *(bf16x8*)&op[(size_t)(c0 + oc) * R + r0 + orr] = v;
}

// ---------------- router: logits -> softmax -> top2 -> lists ----------------
__global__ __launch_bounds__(256) void router_kernel(
    const float* __restrict__ x, const float* __restrict__ rw,
    const float* __restrict__ rb, unsigned int* __restrict__ cnt,
    int* __restrict__ list, float* __restrict__ wq) {
  int wave = threadIdx.x >> 6, lane = threadIdx.x & 63;
  int t = blockIdx.x * 4 + wave;
  if (t >= NTOK) return;
  const float* xr = x + (size_t)t * CDIM;
  float acc[8] = {0.f, 0.f, 0.f, 0.f, 0.f, 0.f, 0.f, 0.f};
  for (int c = lane; c < CDIM; c += 64) {
    float xv = xr[c];
    const float4* rp = (const float4*)(rw + c * 8);
    float4 r0 = rp[0], r1 = rp[1];
    acc[0] += xv * r0.x; acc[1] += xv * r0.y;
    acc[2] += xv * r0.z; acc[3] += xv * r0.w;
    acc[4] += xv * r1.x; acc[5] += xv * r1.y;
    acc[6] += xv * r1.z; acc[7] += xv * r1.w;
  }
#pragma unroll
  for (int e = 0; e < 8; e++)
#pragma unroll
    for (int off = 32; off; off >>= 1) acc[e] += __shfl_down(acc[e], off);
  if (lane == 0) {
    float p[8], mx = -1e30f;
#pragma unroll
    for (int e = 0; e < 8; e++) { p[e] = acc[e] + rb[e]; mx = fmaxf(mx, p[e]); }
    float s = 0.f;
#pragma unroll
    for (int e = 0; e < 8; e++) { p[e] = expf(p[e] - mx); s += p[e]; }
    float inv = 1.0f / s;
#pragma unroll
    for (int e = 0; e < 8; e++) p[e] *= inv;
    int i1 = 0;
#pragma unroll
    for (int e = 1; e < 8; e++) if (p[e] > p[i1]) i1 = e;
    int i2 = (i1 == 0) ? 1 : 0;
#pragma unroll
    for (int e = 0; e < 8; e++) if (e != i1 && p[e] > p[i2]) i2 = e;
    unsigned s0 = atomicAdd(&cnt[i1], 1u);
    list[i1 * NTOK + s0] = t * 2;
    unsigned s1 = atomicAdd(&cnt[i2], 1u);
    list[i2 * NTOK + s1] = t * 2 + 1;
    wq[t * 2] = p[i1];
    wq[t * 2 + 1] = p[i2];
  }
}

// ---- shared GEMM core: 256x128 tile, BK=32, triple-buffer, depth-2 ----
// 8 waves 4Mx2N; per-wave acc 4x4 frags (64 VGPR). 72 KB LDS -> 2 blocks/CU.
// Stage = 3 gld_lds16/thread/tile; counted vmcnt(6)/(3)/(0); 2 barriers/tile.

#define STAGE3(T, AS, BS)                    \
  do {                                       \
    int _k = (T)*BK;                         \
    gld_lds16(aR1 + _k, (AS) + dstA);        \
    gld_lds16(aR2 + _k, (AS) + dstA + 4096); \
    gld_lds16(bR1 + _k, (BS) + dstA);        \
  } while (0)

template <int NT>
__device__ __forceinline__ void gemm_core(const bf16* aR1, const bf16* aR2,
                                          const bf16* bR1, bf16* AsBase,
                                          bf16* BsBase, int tid,
                                          f32x4 (&acc)[4][4]) {
  int w = tid >> 6, l = tid & 63;
  int ln = l & 15, kq = l >> 4;
  int wm = w & 3, wn = w >> 2;               // 4M x 2N
  int rc8 = (kq ^ ((ln >> 1) & 3)) * 8;      // swizzled read chunk
  int aoff = (wm * 64 + ln) * 32 + rc8;
  int boff = (wn * 64 + ln) * 32 + rc8;
  int dstA = (tid >> 2) * 32 + (tid & 3) * 8;  // linear-in-lane dest

  bf16* pA0 = AsBase;            bf16* pB0 = BsBase;
  bf16* pA1 = AsBase + 8192;     bf16* pB1 = BsBase + 4096;
  bf16* pA2 = AsBase + 16384;    bf16* pB2 = BsBase + 8192;

  STAGE3(0, pA0, pB0);
  STAGE3(1, pA1, pB1);

  for (int t = 0; t < NT; ++t) {
    if (t + 2 < NT) {
      STAGE3(t + 2, pA2, pB2);
      asm volatile("s_waitcnt vmcnt(6)" ::: "memory");
    } else if (t + 1 < NT) {
      asm volatile("s_waitcnt vmcnt(3)" ::: "memory");
    } else {
      asm volatile("s_waitcnt vmcnt(0)" ::: "memory");
    }
    __builtin_amdgcn_s_barrier();  // tile t visible block-wide

    bf16x8 af[4], bfr[4];
#pragma unroll
    for (int i = 0; i < 4; i++)
      af[i] = *(const bf16x8*)&pA0[aoff + i * 16 * 32];
#pragma unroll
    for (int j = 0; j < 4; j++)
      bfr[j] = *(const bf16x8*)&pB0[boff + j * 16 * 32];
    __builtin_amdgcn_s_setprio(1);
#pragma unroll
    for (int i = 0; i < 4; i++)
#pragma unroll
      for (int j = 0; j < 4; j++)
        acc[i][j] = __builtin_amdgcn_mfma_f32_16x16x32_bf16(af[i], bfr[j],
                                                            acc[i][j], 0, 0, 0);
    __builtin_amdgcn_s_setprio(0);
    __builtin_amdgcn_s_barrier();  // all reads of tile t done -> buf reusable

    bf16* tA = pA0; pA0 = pA1; pA1 = pA2; pA2 = tA;
    bf16* tB = pB0; pB0 = pB1; pB1 = pB2; pB2 = tB;
  }
}

// ---------------- GEMM1: h[enc] = gelu(xb[t] @ w1[e] + b1[e]) ----------------
__global__ __launch_bounds__(512, 4) void gemm1_kernel(
    const bf16* __restrict__ xb, const bf16* __restrict__ w1b,
    const float* __restrict__ b1, const int* __restrict__ list,
    const unsigned int* __restrict__ cnt, bf16* __restrict__ h) {
  // grid = 32 x 32 x 8 = 8192 blocks; XCD swizzle: e = bid&7
  int bid = blockIdx.x + 32 * (blockIdx.y + 32 * blockIdx.z);
  int wg = (bid & 7) * 1024 + (bid >> 3);
  int n0 = (wg & 31) * BN;
  int mt = (wg >> 5) & 31;
  int e = wg >> 10;
  int count = (int)min(cnt[e], (unsigned)NTOK);
  int m0 = mt * BM;
  if (m0 >= count) return;

  __shared__ __align__(16) bf16 As[3 * BM * BK];  // 48 KB
  __shared__ __align__(16) bf16 Bs[3 * BN * BK];  // 24 KB

  int tid = threadIdx.x;
  int r = tid >> 2;
  int sc8 = ((tid & 3) ^ ((r >> 1) & 3)) * 8;  // pre-swizzled source col

  const int* lp = list + e * NTOK;
  int encA1 = lp[min(m0 + r, count - 1)];
  int encA2 = lp[min(m0 + r + 128, count - 1)];
  const bf16* aR1 = xb + (size_t)(encA1 >> 1) * CDIM + sc8;
  const bf16* aR2 = xb + (size_t)(encA2 >> 1) * CDIM + sc8;
  const bf16* bR1 =
      w1b + (size_t)e * DFF * CDIM + (size_t)(n0 + r) * CDIM + sc8;

  f32x4 acc[4][4] = {};
  gemm_core<CDIM / BK>(aR1, aR2, bR1, As, Bs, tid, acc);

  int w = tid >> 6, l = tid & 63;
  int ln = l & 15, kq = l >> 4;
  int wm = w & 3, wn = w >> 2;
  float b1f[4];
#pragma unroll
  for (int j = 0; j < 4; j++)
    b1f[j] = b1[e * DFF + n0 + wn * 64 + j * 16 + ln];
#pragma unroll
  for (int i = 0; i < 4; i++) {
#pragma unroll
    for (int rr = 0; rr < 4; rr++) {
      int mrow = wm * 64 + i * 16 + kq * 4 + rr;
      if (m0 + mrow < count) {
        int enc = lp[m0 + mrow];
        bf16* hr = h + (size_t)enc * DFF + n0 + wn * 64 + ln;
#pragma unroll
        for (int j = 0; j < 4; j++) {
          float v = acc[i][j][rr] + b1f[j];
          float g = 0.5f * v * (1.0f + erff(v * 0.70710678118654752f));
          hr[j * 16] = (bf16)g;
        }
      }
    }
  }
}

// ------- GEMM2: y[enc] = wq[enc] * (h[enc] @ w2[e] + b2[e]) (plain stores) --
__global__ __launch_bounds__(512, 4) void gemm2_kernel(
    const bf16* __restrict__ h, const bf16* __restrict__ w2b,
    const float* __restrict__ b2, const int* __restrict__ list,
    const unsigned int* __restrict__ cnt, const float* __restrict__ wq,
    float* __restrict__ y) {
  // grid = 8 x 32 x 8 = 2048 blocks; XCD swizzle: e = bid&7
  int bid = blockIdx.x + 8 * (blockIdx.y + 32 * blockIdx.z);
  int wg = (bid & 7) * 256 + (bid >> 3);
  int n0 = (wg & 7) * BN;
  int mt = (wg >> 3) & 31;
  int e = wg >> 8;
  int count = (int)min(cnt[e], (unsigned)NTOK);
  int m0 = mt * BM;
  if (m0 >= count) return;

  __shared__ __align__(16) bf16 As[3 * BM * BK];
  __shared__ __align__(16) bf16 Bs[3 * BN * BK];

  int tid = threadIdx.x;
  int r = tid >> 2;
  int sc8 = ((tid & 3) ^ ((r >> 1) & 3)) * 8;

  const int* lp = list + e * NTOK;
  int encA1 = lp[min(m0 + r, count - 1)];
  int encA2 = lp[min(m0 + r + 128, count - 1)];
  const bf16* aR1 = h + (size_t)encA1 * DFF + sc8;
  const bf16* aR2 = h + (size_t)encA2 * DFF + sc8;
  const bf16* bR1 =
      w2b + (size_t)e * CDIM * DFF + (size_t)(n0 + r) * DFF + sc8;

  f32x4 acc[4][4] = {};
  gemm_core<DFF / BK>(aR1, aR2, bR1, As, Bs, tid, acc);

  int w = tid >> 6, l = tid & 63;
  int ln = l & 15, kq = l >> 4;
  int wm = w & 3, wn = w >> 2;
  float b2f[4];
#pragma unroll
  for (int j = 0; j < 4; j++)
    b2f[j] = b2[e * CDIM + n0 + wn * 64 + j * 16 + ln];
#pragma unroll
  for (int i = 0; i < 4; i++) {
#pragma unroll
    for (int rr = 0; rr < 4; rr++) {
      int mrow = wm * 64 + i * 16 + kq * 4 + rr;
      if (m0 + mrow < count) {
        int enc = lp[m0 + mrow];
        float wt = wq[enc];
        float* yr = y + (size_t)enc * CDIM + n0 + wn * 64 + ln;
#pragma unroll
        for (int j = 0; j < 4; j++)
          yr[j * 16] = wt * (acc[i][j][rr] + b2f[j]);
      }
    }
  }
}

// ---------- combine: out[t] = y[2t] + y[2t+1] (every enc written once) ------
__global__ __launch_bounds__(256) void combine_kernel(
    const float* __restrict__ y, float* __restrict__ out) {
  int idx = (blockIdx.x * 256 + threadIdx.x) * 4;
  int t = idx >> 10;          // token (CDIM=1024)
  int c = idx & 1023;
  const float* y0 = y + ((size_t)(t * 2) << 10) + c;
  float4 a = *(const float4*)y0;
  float4 b = *(const float4*)(y0 + CDIM);
  float4 r;
  r.x = a.x + b.x; r.y = a.y + b.y; r.z = a.z + b.z; r.w = a.w + b.w;
  *(float4*)(out + idx) = r;
}

extern "C" void kernel_launch(void* const* d_in, const int* in_sizes, int n_in,
                              void* d_out, int out_size, void* d_ws,
                              size_t ws_size, hipStream_t stream) {
  const float* x = (const float*)d_in[0];
  const float* rw = (const float*)d_in[1];
  const float* rb = (const float*)d_in[2];
  const float* w1 = (const float*)d_in[3];
  const float* b1 = (const float*)d_in[4];
  const float* w2 = (const float*)d_in[5];
  const float* b2 = (const float*)d_in[6];
  float* out = (float*)d_out;

  char* ws = (char*)d_ws;
  size_t o = 0;
  auto carve = [&](size_t bytes) {
    void* p = ws + o;
    o = (o + bytes + 255) & ~(size_t)255;
    return p;
  };
  bf16* w1b = (bf16*)carve((size_t)EXP * DFF * CDIM * 2);   // 67 MB
  bf16* w2b = (bf16*)carve((size_t)EXP * DFF * CDIM * 2);   // 67 MB
  bf16* h = (bf16*)carve((size_t)2 * NTOK * DFF * 2);       // 134 MB
  bf16* xb = (bf16*)carve((size_t)NTOK * CDIM * 2);         // 17 MB
  int* list = (int*)carve((size_t)EXP * NTOK * 4);
  float* wq = (float*)carve((size_t)2 * NTOK * 4);
  unsigned int* cnt = (unsigned int*)carve(64);
  // y aliases w1b: w1b dead after gemm1; y needs exactly 67,108,864 B.
  float* y = (float*)w1b;

  hipMemsetAsync(cnt, 0, 64, stream);

  convert_x<<<NTOK * CDIM / (256 * 8), 256, 0, stream>>>(x, xb);
  // w1 [E][C][DFF] -> w1b [E][DFF][C]; w2 [E][DFF][C] -> w2b [E][C][DFF]
  transpose_cvt<<<dim3(DFF / 32, CDIM / 64, EXP), 256, 0, stream>>>(w1, w1b,
                                                                    CDIM, DFF);
  transpose_cvt<<<dim3(CDIM / 32, DFF / 64, EXP), 256, 0, stream>>>(w2, w2b,
                                                                    DFF, CDIM);
  router_kernel<<<NTOK / 4, 256, 0, stream>>>(x, rw, rb, cnt, list, wq);
  gemm1_kernel<<<dim3(DFF / BN, NTOK / BM, EXP), 512, 0, stream>>>(
      xb, w1b, b1, list, cnt, h);
  gemm2_kernel<<<dim3(CDIM / BN, NTOK / BM, EXP), 512, 0, stream>>>(
      h, w2b, b2, list, cnt, wq, y);
  combine_kernel<<<NTOK * CDIM / (256 * 4), 256, 0, stream>>>(y, out);
}